// Round 4
// baseline (11908.437 us; speedup 1.0000x reference)
//
#include <hip/hip_runtime.h>
#include <math.h>

// ---------------------------------------------------------------------------
// Seq2SeqLSTM on MI355X -- Round 4: fence-free h-exchange chain.
//
// Round-3 evidence: 16.2us/phase, VALUBusy 7.6% (VALU work only ~2.6us),
// FETCH 615KB/phase == per-XCD weight slices -> the agent-scope acquire
// fence in gbar invalidates L2 every phase; weights re-stream from L3/HBM
// 623 times at 16-wave occupancy (latency-bound).
//
// Fix: only the 128KB h slabs + counters need cross-XCD visibility. All
// slab accesses become agent-scope RELAXED atomics (sc1, cache-bypassing,
// read/write the device coherence point); the barrier uses a relaxed RMW +
// relaxed polls and NO fences. Ordering: publisher sc1 stores are drained
// by the vmcnt(0) the compiler emits before __syncthreads' s_barrier, so
// they are at the coherence point before the arrival RMW; consumer h loads
// issue after poll-exit and also read the coherence point. Weights/xp/b1
// stay resident in K$/L1/L2 across all phases.
// ---------------------------------------------------------------------------

#define B     64
#define SLEN  64
#define TLEN  32
#define HID   256
#define EMBD  256
#define G4    1024
#define VOC   32000
#define NPRED 31
#define NWG   64

__device__ __forceinline__ float sigf(float x){ return 1.0f/(1.0f+__expf(-x)); }

__device__ __forceinline__ void gstoref(float* p, float v){
  __hip_atomic_store(p, v, __ATOMIC_RELAXED, __HIP_MEMORY_SCOPE_AGENT);
}
__device__ __forceinline__ unsigned long long gload64(const unsigned long long* p){
  return __hip_atomic_load(p, __ATOMIC_RELAXED, __HIP_MEMORY_SCOPE_AGENT);
}

// --------------------------------- init ------------------------------------
__global__ void k_init(const int* __restrict__ tgt, int* __restrict__ buf){
  int r = threadIdx.x;
  if (r < B) buf[r*TLEN] = tgt[r*TLEN];
}

__global__ void k_zero(int* __restrict__ ctr){
  ctr[threadIdx.x] = 0;
}

// --------------------------------- xproj -----------------------------------
// out[(pos*G4 + j)*64 + r] = b0[j] + sum_k emb[tok[r]][k] * W[j][k]
__global__ __launch_bounds__(256) void k_xproj(
    const int* __restrict__ tok, int tok_stride, int pos0,
    const float* __restrict__ emb, const float* __restrict__ W,
    const float* __restrict__ b0, float* __restrict__ out)
{
  __shared__ float xT[128][64];
  const int tid  = threadIdx.x;
  const int lane = tid & 63;
  const int wv   = __builtin_amdgcn_readfirstlane(tid >> 6);
  const int pos  = pos0 + blockIdx.y;
  const int jbase= blockIdx.x*32 + wv*8;

  const int rS = tid >> 2, klane = tid & 3;
  const int tokrow = tok[rS*tok_stride + pos];
  const float* xsrc = emb + (size_t)tokrow*EMBD;

  float acc[8];
  #pragma unroll
  for (int jj=0;jj<8;jj++) acc[jj]=0.f;

  for (int c=0;c<2;c++){
    __syncthreads();
    #pragma unroll
    for (int i=0;i<32;i++){
      int k = klane + 4*i;
      xT[k][rS] = xsrc[c*128 + k];
    }
    __syncthreads();
    for (int kc=0;kc<8;kc++){
      float x[16];
      #pragma unroll
      for (int i=0;i<16;i++) x[i] = xT[kc*16+i][lane];
      #pragma unroll
      for (int jj=0;jj<8;jj++){
        const float* Wp = W + (size_t)(jbase+jj)*EMBD + c*128 + kc*16;
        float s = 0.f;
        #pragma unroll
        for (int i=0;i<16;i++) s += Wp[i]*x[i];
        acc[jj] += s;
      }
    }
  }
  #pragma unroll
  for (int jj=0;jj<8;jj++){
    int j = jbase+jj;
    out[((size_t)pos*G4 + j)*64 + lane] = acc[jj] + b0[j];
  }
}

// ---------------------------- device barrier --------------------------------
// Fence-free: relies on (a) __syncthreads draining vmcnt -> all sc1 stores at
// coherence point before arrival; (b) all cross-WG data accesses being sc1
// atomics issued after poll-exit. One-shot counter per phase (pre-zeroed).
__device__ __forceinline__ void gbar(int* __restrict__ c){
  __syncthreads();
  if (threadIdx.x == 0){
    __hip_atomic_fetch_add(c, 1, __ATOMIC_RELAXED, __HIP_MEMORY_SCOPE_AGENT);
    while (__hip_atomic_load(c, __ATOMIC_RELAXED, __HIP_MEMORY_SCOPE_AGENT) < NWG){}
  }
  asm volatile("" ::: "memory");
  __syncthreads();
}

// --------------------------------- chain -----------------------------------
// xp: [p][1024][64]. Weights in original [1024][256] row-major (wave-uniform
// scalar loads, cache-resident). h0T/h1T: [2][256][64] sc1 exchange slabs.
// h0P/h1P/c0P/c1P: persistent state across dispatches (normal ld/st; kernel
// boundaries provide coherence).
__global__ __launch_bounds__(1024) void k_chain4(
    const float* __restrict__ xp, int nsteps,
    const float* __restrict__ Whh0, const float* __restrict__ Wih1,
    const float* __restrict__ Whh1, const float* __restrict__ b1,
    float* __restrict__ h0P, float* __restrict__ h1P,
    float* __restrict__ c0P, float* __restrict__ c1P,
    float* __restrict__ h0T, float* __restrict__ h1T,
    int* __restrict__ ctr, int initzero)
{
  __shared__ __align__(16) float h0s[256][64];   // 64 KB
  __shared__ __align__(16) float h1s[256][64];   // 64 KB
  __shared__ float part[16][4][64];              // 16 KB
  const int tid  = threadIdx.x;
  const int lane = tid & 63;
  const int wv   = __builtin_amdgcn_readfirstlane(tid >> 6);
  const int jsub = wv & 3, kq = wv >> 2;
  const int j    = blockIdx.x*4 + jsub;
  const int k0   = kq << 6;

  const float* Wr0 = Whh0 + ((size_t)(0*HID+j))*HID + k0;
  const float* Wr1 = Whh0 + ((size_t)(1*HID+j))*HID + k0;
  const float* Wr2 = Whh0 + ((size_t)(2*HID+j))*HID + k0;
  const float* Wr3 = Whh0 + ((size_t)(3*HID+j))*HID + k0;
  const float* Wi0 = Wih1 + ((size_t)(0*HID+j))*HID + k0;
  const float* Wi1 = Wih1 + ((size_t)(1*HID+j))*HID + k0;
  const float* Wi2 = Wih1 + ((size_t)(2*HID+j))*HID + k0;
  const float* Wi3 = Wih1 + ((size_t)(3*HID+j))*HID + k0;
  const float* Wh0 = Whh1 + ((size_t)(0*HID+j))*HID + k0;
  const float* Wh1 = Whh1 + ((size_t)(1*HID+j))*HID + k0;
  const float* Wh2 = Whh1 + ((size_t)(2*HID+j))*HID + k0;
  const float* Wh3 = Whh1 + ((size_t)(3*HID+j))*HID + k0;

  float c0 = 0.f, c1 = 0.f;
  float bb0 = 0.f, bb1 = 0.f, bb2 = 0.f, bb3 = 0.f;   // b1 hoisted
  if (wv < 4){
    bb0 = b1[0*HID+j]; bb1 = b1[1*HID+j];
    bb2 = b1[2*HID+j]; bb3 = b1[3*HID+j];
    if (!initzero){
      c0 = c0P[j*64 + lane];
      c1 = c1P[j*64 + lane];
    }
  }

  for (int q = 0; q <= nsteps; ++q){
    if (q) gbar(ctr + q - 1);

    // act-wave prefetch: xp rows for step q (cached loads; L2-resident)
    float xv0=0.f, xv1=0.f, xv2=0.f, xv3=0.f;
    if (wv < 4 && q < nsteps){
      const float* xq = xp + ((size_t)q*G4)*64 + lane;
      xv0 = xq[(0*HID+j)*64]; xv1 = xq[(1*HID+j)*64];
      xv2 = xq[(2*HID+j)*64]; xv3 = xq[(3*HID+j)*64];
    }

    // stage h0s <- h0(q-1); h1s <- h1(q-2)   (sc1 8B loads from slabs)
    {
      if (q == 0){
        float4* d0 = (float4*)&h0s[0][0];
        if (initzero){
          float4 z = make_float4(0.f,0.f,0.f,0.f);
          #pragma unroll
          for (int i=0;i<4;i++) d0[tid + i*1024] = z;
        } else {
          const float4* s0 = (const float4*)h0P;
          #pragma unroll
          for (int i=0;i<4;i++) d0[tid + i*1024] = s0[tid + i*1024];
        }
      } else {
        const unsigned long long* s0 =
          (const unsigned long long*)(h0T + (size_t)((q-1)&1)*16384);
        unsigned long long* d0 = (unsigned long long*)&h0s[0][0];
        #pragma unroll
        for (int i=0;i<8;i++) d0[tid + i*1024] = gload64(s0 + tid + i*1024);
      }
      if (q <= 1){
        float4* d1 = (float4*)&h1s[0][0];
        if (initzero){
          float4 z = make_float4(0.f,0.f,0.f,0.f);
          #pragma unroll
          for (int i=0;i<4;i++) d1[tid + i*1024] = z;
        } else {
          const float4* s1 = (const float4*)h1P;
          #pragma unroll
          for (int i=0;i<4;i++) d1[tid + i*1024] = s1[tid + i*1024];
        }
      } else {
        const unsigned long long* s1 =
          (const unsigned long long*)(h1T + (size_t)(q&1)*16384);
        unsigned long long* d1 = (unsigned long long*)&h1s[0][0];
        #pragma unroll
        for (int i=0;i<8;i++) d1[tid + i*1024] = gload64(s1 + tid + i*1024);
      }
    }
    __syncthreads();   // h0s/h1s ready

    // ---- L0 partials for step q
    float a0=0.f,a1=0.f,a2=0.f,a3=0.f;
    if (q < nsteps){
      #pragma unroll 8
      for (int k=0;k<64;k++){
        float h = h0s[k0+k][lane];
        a0 += Wr0[k]*h; a1 += Wr1[k]*h; a2 += Wr2[k]*h; a3 += Wr3[k]*h;
      }
      part[wv][0][lane]=a0; part[wv][1][lane]=a1;
      part[wv][2][lane]=a2; part[wv][3][lane]=a3;
    }
    __syncthreads();   // pL0 complete

    // act0: reduce + activate + publish h0(q) to slab (sc1)
    if (wv < 4 && q < nsteps){
      float g0=xv0, g1=xv1, g2=xv2, g3=xv3;
      #pragma unroll
      for (int kk=0;kk<4;kk++){
        g0 += part[kk*4+wv][0][lane]; g1 += part[kk*4+wv][1][lane];
        g2 += part[kk*4+wv][2][lane]; g3 += part[kk*4+wv][3][lane];
      }
      c0 = sigf(g1)*c0 + sigf(g0)*tanhf(g2);
      float h = sigf(g3)*tanhf(c0);
      gstoref(&h0T[(size_t)(q&1)*16384 + j*64 + lane], h);
      if (q == nsteps-1) h0P[j*64 + lane] = h;   // for next dispatch (normal)
    }

    // ---- L1 partials for step q-1 (h0s = h0(q-1), h1s = h1(q-2))
    float b0a=0.f,b1a=0.f,b2a=0.f,b3a=0.f;
    if (q >= 1){
      #pragma unroll 8
      for (int k=0;k<64;k++){
        float ha = h0s[k0+k][lane];
        float hb = h1s[k0+k][lane];
        b0a += Wi0[k]*ha + Wh0[k]*hb;
        b1a += Wi1[k]*ha + Wh1[k]*hb;
        b2a += Wi2[k]*ha + Wh2[k]*hb;
        b3a += Wi3[k]*ha + Wh3[k]*hb;
      }
    }
    __syncthreads();   // act0 done reading pL0
    if (q >= 1){
      part[wv][0][lane]=b0a; part[wv][1][lane]=b1a;
      part[wv][2][lane]=b2a; part[wv][3][lane]=b3a;
    }
    __syncthreads();   // pL1 complete

    // act1: reduce + activate + publish h1(q-1) to slab (sc1)
    if (wv < 4 && q >= 1){
      float g0=bb0, g1=bb1, g2=bb2, g3=bb3;
      #pragma unroll
      for (int kk=0;kk<4;kk++){
        g0 += part[kk*4+wv][0][lane]; g1 += part[kk*4+wv][1][lane];
        g2 += part[kk*4+wv][2][lane]; g3 += part[kk*4+wv][3][lane];
      }
      c1 = sigf(g1)*c1 + sigf(g0)*tanhf(g2);
      float h = sigf(g3)*tanhf(c1);
      gstoref(&h1T[(size_t)((q-1)&1)*16384 + j*64 + lane], h);
      if (q == nsteps) h1P[j*64 + lane] = h;     // for pred (kernel boundary)
    }
  }

  if (wv < 4){
    c0P[j*64 + lane] = c0;
    c1P[j*64 + lane] = c1;
  }
}

// --------------------------------- pred ------------------------------------
__global__ __launch_bounds__(256) void k_pred(
    const float* __restrict__ h1, const float* __restrict__ Wout,
    const float* __restrict__ bout, float* __restrict__ dout, int t,
    float* __restrict__ pval, int* __restrict__ pidx)
{
  __shared__ float xT[128][64];
  __shared__ float cval[4][64];
  __shared__ int   cidx[4][64];
  const int tid  = threadIdx.x;
  const int lane = tid & 63;
  const int wv   = __builtin_amdgcn_readfirstlane(tid >> 6);
  const int vbase= blockIdx.x*32 + wv*8;

  float acc[8];
  #pragma unroll
  for (int vv=0;vv<8;vv++) acc[vv]=0.f;

  for (int c=0;c<2;c++){
    __syncthreads();
    {
      const float4* s4 = (const float4*)(h1 + c*8192);
      float4* d4 = (float4*)&xT[0][0];
      #pragma unroll
      for (int i=0;i<8;i++) d4[tid + i*256] = s4[tid + i*256];
    }
    __syncthreads();
    for (int kc=0;kc<8;kc++){
      float x[16];
      #pragma unroll
      for (int i=0;i<16;i++) x[i] = xT[kc*16+i][lane];
      #pragma unroll
      for (int vv=0;vv<8;vv++){
        const float* Wp = Wout + (size_t)(vbase+vv)*HID + c*128 + kc*16;
        float s = 0.f;
        #pragma unroll
        for (int i=0;i<16;i++) s += Wp[i]*x[i];
        acc[vv] += s;
      }
    }
  }

  const int r = lane;
  float best = -INFINITY; int bi = 0;
  #pragma unroll
  for (int vv=0; vv<8; vv++){
    int v = vbase + vv;
    float val = acc[vv] + bout[v];
    dout[((size_t)r*NPRED + t)*VOC + v] = val;
    if (val > best){ best = val; bi = v; }
  }
  cval[wv][lane] = best; cidx[wv][lane] = bi;
  __syncthreads();
  if (tid < 64){
    float bb = cval[0][tid]; int bbi = cidx[0][tid];
    #pragma unroll
    for (int w=1; w<4; w++){
      float v = cval[w][tid];
      if (v > bb){ bb = v; bbi = cidx[w][tid]; }
    }
    pval[(size_t)tid*1024 + blockIdx.x] = bb;
    pidx[(size_t)tid*1024 + blockIdx.x] = bbi;
  }
}

// ------------------------------ argmax final --------------------------------
__global__ __launch_bounds__(256) void k_amax(
    const float* __restrict__ pval, const int* __restrict__ pidx,
    int* __restrict__ buf, int t)
{
  __shared__ float sv[256]; __shared__ int si[256];
  const int r = blockIdx.x, tid = threadIdx.x;
  float best = -INFINITY; int bi = 0x7fffffff;
  for (int w = tid; w < 1000; w += 256){
    float v = pval[(size_t)r*1024 + w]; int ii = pidx[(size_t)r*1024 + w];
    if (v > best || (v == best && ii < bi)){ best = v; bi = ii; }
  }
  sv[tid] = best; si[tid] = bi;
  __syncthreads();
  for (int s2 = 128; s2 > 0; s2 >>= 1){
    if (tid < s2){
      float v = sv[tid+s2]; int ii = si[tid+s2];
      if (v > sv[tid] || (v == sv[tid] && ii < si[tid])){ sv[tid]=v; si[tid]=ii; }
    }
    __syncthreads();
  }
  if (tid == 0) buf[r*TLEN + t + 1] = si[0];
}

// -------------------------------- launch ------------------------------------
extern "C" void kernel_launch(void* const* d_in, const int* in_sizes, int n_in,
                              void* d_out, int out_size, void* d_ws, size_t ws_size,
                              hipStream_t stream)
{
  const int*   input_seq  = (const int*)d_in[0];
  const int*   target_seq = (const int*)d_in[1];
  const float* enc_emb = (const float*)d_in[2];
  const float* dec_emb = (const float*)d_in[3];
  const float* enc_Wih = (const float*)d_in[4];
  const float* enc_Whh = (const float*)d_in[5];
  const float* enc_b   = (const float*)d_in[6];
  const float* dec_Wih = (const float*)d_in[7];
  const float* dec_Whh = (const float*)d_in[8];
  const float* dec_b   = (const float*)d_in[9];
  const float* W_out   = (const float*)d_in[10];
  const float* b_out   = (const float*)d_in[11];
  float* out = (float*)d_out;

  float* ws   = (float*)d_ws;
  float* xp_e = ws;                               // 64*1024*64
  float* xp_d = xp_e + (size_t)SLEN*G4*64;        // 32*1024*64
  float* h0P  = xp_d + (size_t)TLEN*G4*64;        // 256*64
  float* h1P  = h0P + HID*64;
  float* c0P  = h1P + HID*64;
  float* c1P  = c0P + HID*64;
  float* h0T  = c1P + HID*64;                     // 2*256*64
  float* h1T  = h0T + 2*HID*64;                   // 2*256*64
  float* pval = h1T + 2*HID*64;                   // 64*1024
  int*   pidx = (int*)(pval + (size_t)B*1024);    // 64*1024
  int*   buf  = pidx + (size_t)B*1024;            // 64*32
  int*   ctr  = buf + B*TLEN;                     // 1024 barrier slots

  k_init<<<1, 64, 0, stream>>>(target_seq, buf);
  k_zero<<<1, 1024, 0, stream>>>(ctr);

  // encoder
  k_xproj<<<dim3(32, SLEN), 256, 0, stream>>>(input_seq, SLEN, 0, enc_emb,
        enc_Wih, enc_b, xp_e);
  k_chain4<<<NWG, 1024, 0, stream>>>(xp_e, SLEN,
        enc_Whh, enc_Wih + (size_t)G4*EMBD, enc_Whh + (size_t)G4*HID,
        enc_b + G4, h0P, h1P, c0P, c1P, h0T, h1T, ctr, 1);

  // decoder greedy loop (outer step t replays positions 0..t)
  int coff = SLEN;
  for (int t = 0; t < NPRED; t++){
    k_xproj<<<dim3(32, 1), 256, 0, stream>>>(buf, TLEN, t, dec_emb,
        dec_Wih, dec_b, xp_d);
    k_chain4<<<NWG, 1024, 0, stream>>>(xp_d, t+1,
        dec_Whh, dec_Wih + (size_t)G4*EMBD, dec_Whh + (size_t)G4*HID,
        dec_b + G4, h0P, h1P, c0P, c1P, h0T, h1T, ctr + coff, 0);
    coff += t + 1;
    k_pred<<<1000, 256, 0, stream>>>(h1P, W_out, b_out, out, t, pval, pidx);
    k_amax<<<B, 256, 0, stream>>>(pval, pidx, buf, t);
  }
}